// Round 12
// baseline (142.736 us; speedup 1.0000x reference)
//
#include <hip/hip_runtime.h>

// GCN aggregation: out[t] = norm[t] * sum_{e:dst=t} norm[src]*x[src] + EPS*x[t]
// Round 21: partition grid fix on the round-20 (proven-best, 140.1 us) base.
// Evidence: at EPB=8192 partition's grid is E/8192 = 153 blocks < 256 CUs ->
// 40% of the chip fully idle during partition, zero inter-block latency hiding
// for the scattered rec/srec writes. EPB -> 4096 (306 blocks, all CUs busy,
// ~9.6 waves/CU). Fragments drop 84->42B (rec) / 21->10B (srec): some write
// amp, but doubled hiding capacity should dominate (r1/r2's opposite trade was
// confounded by scratch spill + global deg atomics, both long gone).
// degnorm 256->512 threads (NB-block grid also starved). Everything else
// unchanged. 5 launches + 1 tiny memset.
constexpr int D        = 64;
constexpr float EPS    = 0.5f;
constexpr int BKT      = 256;    // nodes per bucket
constexpr int CAPB_MAX = 4096;
constexpr int EPB      = 4096;   // edges per partition block
constexpr int PTHREADS = 512;
constexpr int EPT      = EPB / PTHREADS;   // 8
constexpr int GTHREADS = 1024;   // sortgather block size (16 waves)
constexpr int NTHREADS = 512;    // degnorm block size
constexpr int NBMAX    = 512;    // max node buckets (n <= 131072)
constexpr int MAXOVF   = 65536;

__device__ __forceinline__ unsigned int f2bf(float f) {
    unsigned int u = __float_as_uint(f);
    return (u + 0x7FFFu + ((u >> 16) & 1u)) >> 16;   // RNE to bf16
}
__device__ __forceinline__ float bf2f_lo(unsigned int v) { return __uint_as_float(v << 16); }
__device__ __forceinline__ float bf2f_hi(unsigned int v) { return __uint_as_float(v & 0xFFFF0000u); }

// ---------------- main path ----------------

// Scatter edges into shared per-bucket arrays rec[b*capb..] (dst-bucketed,
// packed (s<<8)|(t&255)) and srec[b*capb..] (src-bucketed bytes). Per-
// (block,bucket) reserve via one global atomic; per-edge rank via LDS atomic.
__global__ __launch_bounds__(PTHREADS)
void partition_kernel(const int* __restrict__ src, const int* __restrict__ dst,
                      int* __restrict__ curD, int* __restrict__ curS,
                      unsigned int* __restrict__ rec, unsigned char* __restrict__ srec,
                      int* __restrict__ ovf_cnt, int* __restrict__ ovf,
                      int* __restrict__ sovf_cnt, int* __restrict__ sovf,
                      int E, int NB, int capb) {
    __shared__ int histD[NBMAX];   // count, then rank
    __shared__ int histS[NBMAX];
    __shared__ int startD[NBMAX];
    __shared__ int startS[NBMAX];
    const int base = blockIdx.x * EPB;
    const int tid  = threadIdx.x;
    const bool full = (base + EPB) <= E;
    for (int b = tid; b < NB; b += PTHREADS) { histD[b] = 0; histS[b] = 0; }
    __syncthreads();

    // ---- pass 1: count ----
    if (full) {
        const int4* s4 = (const int4*)(src + base);
        const int4* d4 = (const int4*)(dst + base);
        #pragma unroll
        for (int k = 0; k < EPT / 4; ++k) {
            int4 sv = s4[tid + k * PTHREADS];
            int4 dv = d4[tid + k * PTHREADS];
            atomicAdd(&histD[dv.x >> 8], 1); atomicAdd(&histS[sv.x >> 8], 1);
            atomicAdd(&histD[dv.y >> 8], 1); atomicAdd(&histS[sv.y >> 8], 1);
            atomicAdd(&histD[dv.z >> 8], 1); atomicAdd(&histS[sv.z >> 8], 1);
            atomicAdd(&histD[dv.w >> 8], 1); atomicAdd(&histS[sv.w >> 8], 1);
        }
    } else {
        for (int k = 0; k < EPT; ++k) {
            int e = base + tid + k * PTHREADS;
            if (e < E) {
                atomicAdd(&histD[dst[e] >> 8], 1);
                atomicAdd(&histS[src[e] >> 8], 1);
            }
        }
    }
    __syncthreads();
    // ---- reserve: one global atomic per (block,bucket) ----
    for (int b = tid; b < NB; b += PTHREADS) {
        int c = histD[b];
        startD[b] = (c > 0) ? atomicAdd(&curD[b], c) : 0;
        histD[b] = 0;                          // reuse as rank
        int c2 = histS[b];
        startS[b] = (c2 > 0) ? atomicAdd(&curS[b], c2) : 0;
        histS[b] = 0;
    }
    __syncthreads();
    // ---- pass 2: place (re-read src/dst; L2-resident) ----
    if (full) {
        const int4* s4 = (const int4*)(src + base);
        const int4* d4 = (const int4*)(dst + base);
        #pragma unroll
        for (int k = 0; k < EPT / 4; ++k) {
            int4 sv = s4[tid + k * PTHREADS];
            int4 dv = d4[tid + k * PTHREADS];
            int ss[4] = {sv.x, sv.y, sv.z, sv.w};
            int tt[4] = {dv.x, dv.y, dv.z, dv.w};
            #pragma unroll
            for (int j = 0; j < 4; ++j) {
                int s = ss[j], t = tt[j];
                int bD = t >> 8;
                int r  = atomicAdd(&histD[bD], 1);
                int p  = startD[bD] + r;       // zero-based within bucket
                if (p < capb) {
                    rec[(size_t)bD * capb + p] = ((unsigned int)s << 8) | (unsigned int)(t & (BKT - 1));
                } else {
                    int i = atomicAdd(ovf_cnt, 1);
                    if (i < MAXOVF) { ovf[2 * i] = s; ovf[2 * i + 1] = t; }
                }
                int bS = s >> 8;
                int r2 = atomicAdd(&histS[bS], 1);
                int p2 = startS[bS] + r2;
                if (p2 < capb) {
                    srec[(size_t)bS * capb + p2] = (unsigned char)(s & (BKT - 1));
                } else {
                    int i = atomicAdd(sovf_cnt, 1);
                    if (i < MAXOVF) sovf[i] = s;
                }
            }
        }
    } else {
        for (int k = 0; k < EPT; ++k) {
            int e = base + tid + k * PTHREADS;
            if (e < E) {
                int s = src[e], t = dst[e];
                int bD = t >> 8;
                int r  = atomicAdd(&histD[bD], 1);
                int p  = startD[bD] + r;
                if (p < capb) {
                    rec[(size_t)bD * capb + p] = ((unsigned int)s << 8) | (unsigned int)(t & (BKT - 1));
                } else {
                    int i = atomicAdd(ovf_cnt, 1);
                    if (i < MAXOVF) { ovf[2 * i] = s; ovf[2 * i + 1] = t; }
                }
                int bS = s >> 8;
                int r2 = atomicAdd(&histS[bS], 1);
                int p2 = startS[bS] + r2;
                if (p2 < capb) {
                    srec[(size_t)bS * capb + p2] = (unsigned char)(s & (BKT - 1));
                } else {
                    int i = atomicAdd(sovf_cnt, 1);
                    if (i < MAXOVF) sovf[i] = s;
                }
            }
        }
    }
}

// Per-bucket out-degree histogram from CONTIGUOUS srec[b*capb..] -> norm[].
__global__ __launch_bounds__(NTHREADS)
void degnorm_kernel(const unsigned char* __restrict__ srec, const int* __restrict__ curS,
                    const int* __restrict__ sovf_cnt, const int* __restrict__ sovf,
                    float* __restrict__ norm, int n, int capb) {
    const int b   = blockIdx.x;
    const int tid = threadIdx.x;
    __shared__ int hist[BKT];
    if (tid < BKT) hist[tid] = 0;
    __syncthreads();
    int cnt = curS[b];
    if (cnt > capb) cnt = capb;
    const unsigned int* s4 = (const unsigned int*)(srec + (size_t)b * capb);  // capb % 4 == 0
    int nw = cnt >> 2;
    for (int i = tid; i < nw; i += NTHREADS) { // word-wise coalesced
        unsigned int w = s4[i];
        atomicAdd(&hist[w & 255u], 1);
        atomicAdd(&hist[(w >> 8) & 255u], 1);
        atomicAdd(&hist[(w >> 16) & 255u], 1);
        atomicAdd(&hist[w >> 24], 1);
    }
    for (int i = (nw << 2) + tid; i < cnt; i += NTHREADS)
        atomicAdd(&hist[srec[(size_t)b * capb + i]], 1);
    int oc = *sovf_cnt;                        // expected 0
    if (oc > 0) {
        if (oc > MAXOVF) oc = MAXOVF;
        for (int i = tid; i < oc; i += NTHREADS) {
            int s = sovf[i];
            if ((s >> 8) == b) atomicAdd(&hist[s & (BKT - 1)], 1);
        }
    }
    __syncthreads();
    if (tid < BKT) {
        int node = b * BKT + tid;
        if (node < n) norm[node] = rsqrtf(fmaxf((float)hist[tid], 1.0f));
    }
}

// Pure streaming: yh = bf16(norm * x). Grid-strided, full HBM bandwidth.
__global__ __launch_bounds__(256)
void yhconv_kernel(const float2* __restrict__ x2, const float* __restrict__ norm,
                   unsigned int* __restrict__ yh, int total) {
    int stride = gridDim.x * 256;
    for (int i = blockIdx.x * 256 + threadIdx.x; i < total; i += stride) {
        float2 v = x2[i];
        float nm = norm[i >> 5];               // 32 float2 per node; broadcast load
        yh[i] = f2bf(v.x * nm) | (f2bf(v.y * nm) << 16);
    }
}

// One block per bucket (1024 threads = 16 waves, ~39 KB LDS). CONTIGUOUS read
// of the bucket's records (coalesced, no segment tables), LDS counting sort to
// per-node src lists (shfl scan, 2 barriers), then gather yh rows: 8 nodes per
// wave (8 lanes x uint4 = 128B row), 8-deep unroll for MLP.
__global__ __launch_bounds__(GTHREADS)
void sortgather_kernel(const unsigned int* __restrict__ rec, const int* __restrict__ curD,
                       const float* __restrict__ norm, const uint4* __restrict__ yr4,
                       const float4* __restrict__ x4, float4* __restrict__ out4,
                       int n, int capb) {
    __shared__ unsigned int recs[CAPB_MAX];   // 16 KB
    __shared__ unsigned int srcs[CAPB_MAX];   // 16 KB
    __shared__ int hist[BKT];                 // per-node in-count (pristine after scan)
    __shared__ int rankb[BKT];
    __shared__ int rsL[BKT];                  // per-node exclusive start (pristine)
    __shared__ float nrmL[BKT];               // per-node dst norm
    __shared__ unsigned int wsums[GTHREADS / 64];
    const int b   = blockIdx.x;
    const int tid = threadIdx.x;
    const int lane = tid & 63;
    const int wid  = tid >> 6;

    int cnt = curD[b];
    if (cnt > capb) cnt = capb;
    for (int i = tid; i < cnt; i += GTHREADS) recs[i] = rec[(size_t)b * capb + i];
    if (tid < BKT) {
        hist[tid] = 0;
        int node = b * BKT + tid;
        nrmL[tid] = (node < n) ? norm[node] : 1.0f;
    }
    __syncthreads();
    for (int i = tid; i < cnt; i += GTHREADS) atomicAdd(&hist[recs[i] & (BKT - 1)], 1);
    __syncthreads();
    // ---- per-wave shfl inclusive scan over hist[0..BKT) (threads 0..255) ----
    {
        int v = (tid < BKT) ? hist[tid] : 0;
        #pragma unroll
        for (int off = 1; off < 64; off <<= 1) {
            int t = __shfl_up(v, off);
            if (lane >= off) v += t;
        }
        if (tid < BKT && lane == 63) wsums[wid] = (unsigned int)v;
        __syncthreads();
        if (tid < BKT) {
            int add = 0;
            #pragma unroll
            for (int w = 0; w < BKT / 64; ++w)
                if (w < wid) add += (int)wsums[w];
            int excl = v + add - hist[tid];
            rankb[tid] = excl;
            rsL[tid]   = excl;
        }
    }
    __syncthreads();
    for (int i = tid; i < cnt; i += GTHREADS) {
        unsigned int v = recs[i];
        int pos = atomicAdd(&rankb[v & (BKT - 1)], 1);
        srcs[pos] = v >> 8;
    }
    __syncthreads();

    // ---- gather phase: 16 waves x 8 nodes -> 128 nodes/round, 2 rounds ----
    const int fl  = lane & 7;                  // uint4 index within 128B row
    const int oct = lane >> 3;                 // node within 8-node group
    #pragma unroll
    for (int r = 0; r < BKT / 128; ++r) {
        int ln   = r * 128 + wid * 8 + oct;    // local node 0..255
        int node = b * BKT + ln;
        bool valid = node < n;
        int rsl = valid ? rsL[ln]  : 0;
        int cl  = valid ? hist[ln] : 0;
        int m = cl;                            // uniform loop count = wave-max
        m = max(m, __shfl_xor(m, 8));
        m = max(m, __shfl_xor(m, 16));
        m = max(m, __shfl_xor(m, 32));
        float a0 = 0.f, a1 = 0.f, a2 = 0.f, a3 = 0.f;
        float a4 = 0.f, a5 = 0.f, a6 = 0.f, a7 = 0.f;
        for (int k = 0; k < m; k += 8) {
            int sb[8];
            #pragma unroll
            for (int j = 0; j < 8; ++j) {      // 8 LDS reads issue together
                int kj = k + j;
                sb[j] = (kj < cl) ? (int)srcs[rsl + kj] : -1;
            }
            #pragma unroll
            for (int j = 0; j < 8; ++j) {      // 8 row loads in flight
                bool take = sb[j] >= 0;
                int s = take ? sb[j] : 0;      // dummy hits node 0's cached row
                uint4 v = yr4[(size_t)s * 8 + fl];
                if (!take) { v.x = 0u; v.y = 0u; v.z = 0u; v.w = 0u; }
                a0 += bf2f_lo(v.x); a1 += bf2f_hi(v.x);
                a2 += bf2f_lo(v.y); a3 += bf2f_hi(v.y);
                a4 += bf2f_lo(v.z); a5 += bf2f_hi(v.z);
                a6 += bf2f_lo(v.w); a7 += bf2f_hi(v.w);
            }
        }
        if (valid) {
            float nt = nrmL[ln];
            size_t basei = (size_t)node * 16 + fl * 2;
            float4 xv0 = x4[basei], xv1 = x4[basei + 1];
            float4 r0, r1;
            r0.x = a0 * nt + EPS * xv0.x;  r0.y = a1 * nt + EPS * xv0.y;
            r0.z = a2 * nt + EPS * xv0.z;  r0.w = a3 * nt + EPS * xv0.w;
            r1.x = a4 * nt + EPS * xv1.x;  r1.y = a5 * nt + EPS * xv1.y;
            r1.z = a6 * nt + EPS * xv1.z;  r1.w = a7 * nt + EPS * xv1.w;
            out4[basei] = r0;              // coalesced: 32B/lane
            out4[basei + 1] = r1;
        }
    }
}

// rare: dst-bucket overflow edges (expected 0)
__global__ void cleanup_kernel(const float* __restrict__ x, const float* __restrict__ norm,
                               const int* __restrict__ ovf_cnt, const int* __restrict__ ovf,
                               float* __restrict__ out) {
    int cnt = *ovf_cnt;
    if (cnt > MAXOVF) cnt = MAXOVF;
    long long total = (long long)cnt * D;
    long long stride = (long long)gridDim.x * blockDim.x;
    for (long long i = blockIdx.x * (long long)blockDim.x + threadIdx.x; i < total; i += stride) {
        int e = (int)(i >> 6), d = (int)(i & 63);
        int s = ovf[2 * e], t = ovf[2 * e + 1];
        atomicAdd(&out[(size_t)t * D + d], norm[s] * norm[t] * x[(size_t)s * D + d]);
    }
}

// ---------------- tiny-ws / big-n fallback (round-1 proven) ----------------

__global__ void fb_hist(const int* __restrict__ src, int* __restrict__ deg, int E) {
    int e = blockIdx.x * blockDim.x + threadIdx.x;
    if (e < E) atomicAdd(&deg[src[e]], 1);
}
__global__ void fb_norm(const int* __restrict__ deg, float* __restrict__ norm, int n) {
    int i = blockIdx.x * blockDim.x + threadIdx.x;
    if (i < n) norm[i] = rsqrtf(fmaxf((float)deg[i], 1.0f));
}
__global__ void fb_init_out(const float4* __restrict__ x, float4* __restrict__ out, int n4) {
    int i = blockIdx.x * blockDim.x + threadIdx.x;
    if (i < n4) {
        float4 v = x[i];
        out[i] = make_float4(v.x * EPS, v.y * EPS, v.z * EPS, v.w * EPS);
    }
}
__global__ void fb_scatter(const float* __restrict__ x, const int* __restrict__ src,
                           const int* __restrict__ dst, const float* __restrict__ norm,
                           float* __restrict__ out, int E) {
    long long tid = (long long)blockIdx.x * blockDim.x + threadIdx.x;
    int e = (int)(tid >> 6), d = (int)(tid & 63);
    if (e < E) {
        int s = src[e], t = dst[e];
        atomicAdd(&out[(size_t)t * D + d], norm[s] * norm[t] * x[(size_t)s * D + d]);
    }
}

// ---------------- launcher ----------------

extern "C" void kernel_launch(void* const* d_in, const int* in_sizes, int n_in,
                              void* d_out, int out_size, void* d_ws, size_t ws_size,
                              hipStream_t stream) {
    const float* x   = (const float*)d_in[0];
    const int*   src = (const int*)d_in[1];
    const int*   dst = (const int*)d_in[2];
    float* out = (float*)d_out;

    const int ND = in_sizes[0];
    const int E  = in_sizes[1];
    const int n  = ND / D;
    const int NB = (n + BKT - 1) / BKT;
    constexpr int B = 256;
    const int NB64 = (NB + 63) & ~63;

    int capb = 0;
    for (int c : {4096, 3584}) {               // divisible by 16
        size_t srecB = ((size_t)NB * c + 15) & ~15ull;
        size_t need = (size_t)NB * c * 4                // rec (packed u32)
                    + srecB                             // srec (u8)
                    + (size_t)ND * 2                    // yh
                    + (size_t)n * 4                     // norm
                    + (size_t)(2 * NB64 + 128) * 4      // curD, curS, ovf_cnt, sovf_cnt
                    + (size_t)3 * MAXOVF * 4;           // ovf + sovf
        if (need <= ws_size) { capb = c; break; }
    }

    if (NB <= NBMAX && capb > 0 && n < (1 << 24) && E > 0) {
        unsigned int* rec   = (unsigned int*)d_ws;                        // NB*capb u32
        unsigned char* srec = (unsigned char*)(rec + (size_t)NB * capb);  // NB*capb u8
        size_t srecB        = ((size_t)NB * capb + 15) & ~15ull;
        unsigned int* yh    = (unsigned int*)(srec + srecB);              // ND/2 u32
        float* norm         = (float*)(yh + ND / 2);                      // n
        int* curD           = (int*)(norm + n);                           // NB64
        int* curS           = curD + NB64;                                // NB64
        int* ovf_cnt        = curS + NB64;                                // 64
        int* sovf_cnt       = ovf_cnt + 64;                               // 64
        int* ovf            = sovf_cnt + 64;                              // 2*MAXOVF
        int* sovf           = ovf + 2 * MAXOVF;                           // MAXOVF

        // curD + curS + ovf_cnt + sovf_cnt zeroed in one DMA memset
        hipMemsetAsync(curD, 0, (size_t)(2 * NB64 + 128) * 4, stream);
        partition_kernel<<<(E + EPB - 1) / EPB, PTHREADS, 0, stream>>>(src, dst, curD, curS,
                                                                       rec, srec, ovf_cnt, ovf,
                                                                       sovf_cnt, sovf, E, NB, capb);
        degnorm_kernel<<<NB, NTHREADS, 0, stream>>>(srec, curS, sovf_cnt, sovf, norm, n, capb);
        int yt = ND / 2;
        int yg = (yt + 255) / 256; if (yg > 2048) yg = 2048;
        yhconv_kernel<<<yg, B, 0, stream>>>((const float2*)x, norm, yh, yt);
        sortgather_kernel<<<NB, GTHREADS, 0, stream>>>(rec, curD, norm, (const uint4*)yh,
                                                       (const float4*)x, (float4*)out, n, capb);
        cleanup_kernel<<<32, B, 0, stream>>>(x, norm, ovf_cnt, ovf, out);
    } else {
        int*   deg  = (int*)d_ws;
        float* norm = (float*)d_ws + n;
        hipMemsetAsync(deg, 0, (size_t)n * sizeof(int), stream);
        fb_hist<<<(E + B - 1) / B, B, 0, stream>>>(src, deg, E);
        fb_norm<<<(n + B - 1) / B, B, 0, stream>>>(deg, norm, n);
        fb_init_out<<<(ND / 4 + B - 1) / B, B, 0, stream>>>((const float4*)x, (float4*)out, ND / 4);
        long long total = (long long)E * D;
        fb_scatter<<<(int)((total + B - 1) / B), B, 0, stream>>>(x, src, dst, norm, out, E);
    }
}